// Round 3
// baseline (455.755 us; speedup 1.0000x reference)
//
#include <hip/hip_runtime.h>
#include <hip/hip_bf16.h>

#define ENC_DIM 2048
#define DEC_DIM 512
#define ATT_DIM 512
#define NB 256
#define NP 196
#define M_TOT (NB * NP)   // 50176 = 784 * 64
#define BM 64
#define BK 64
#define NSTEP (ENC_DIM / BK)  // 32

typedef __attribute__((ext_vector_type(8))) short short8;
typedef __attribute__((ext_vector_type(4))) float f32x4;

// ---------------------------------------------------------------------------
// async global->LDS, 16 bytes per lane
// ---------------------------------------------------------------------------
__device__ __forceinline__ void gll16(const float* g, float* l) {
    __builtin_amdgcn_global_load_lds((const __attribute__((address_space(1))) void*)g,
                                     (__attribute__((address_space(3))) void*)l,
                                     16, 0, 0);
}

// ---------------------------------------------------------------------------
// Kernel 1 (fused): blocks [0,512): pack W_enc -> Btt bf16 tiled
//   Btt[J][n][kg][8], J=k/32, n, kg=(k%32)/8  (B-frag = contiguous 1KB/wave)
// blocks [512,768): att2f[b][n] = dec[b]@W_dec[:,n] + b_dec[n] + b_enc[n]
// ---------------------------------------------------------------------------
__global__ __launch_bounds__(256) void prep_kernel(const float* __restrict__ W,
                                                   __hip_bfloat16* __restrict__ Btt,
                                                   const float* __restrict__ dec,
                                                   const float* __restrict__ W_dec,
                                                   const float* __restrict__ b_dec,
                                                   const float* __restrict__ b_enc,
                                                   float* __restrict__ att2f) {
    __shared__ float ds[DEC_DIM];
    if (blockIdx.x < 512) {
        const int gid = blockIdx.x * 256 + threadIdx.x;  // 0..131071
        const int kg = gid & 3;
        const int n  = (gid >> 2) & 511;
        const int J  = gid >> 11;
        const int k  = J * 32 + kg * 8;
        union { short8 v; __hip_bfloat16 h[8]; } u;
        #pragma unroll
        for (int i = 0; i < 8; ++i)
            u.h[i] = __float2bfloat16(W[(size_t)(k + i) * ATT_DIM + n]);
        *(short8*)((short*)Btt + (size_t)gid * 8) = u.v;
    } else {
        const int b = blockIdx.x - 512;
        const int t = threadIdx.x;
        ds[t]       = dec[(size_t)b * DEC_DIM + t];
        ds[t + 256] = dec[(size_t)b * DEC_DIM + t + 256];
        __syncthreads();
        #pragma unroll
        for (int j = 0; j < 2; ++j) {
            const int n = t + j * 256;
            float s = 0.f;
            #pragma unroll 8
            for (int k = 0; k < DEC_DIM; ++k)
                s += ds[k] * W_dec[(size_t)k * ATT_DIM + n];
            att2f[(size_t)b * ATT_DIM + n] = s + b_dec[n] + b_enc[n];
        }
    }
}

// ---------------------------------------------------------------------------
// Kernel 2: e[m] = sum_n relu(enc[m,:]@W_enc[:,n] + att2f[b,n]) * W_att[n]
// BM=64 x BN=512, BK=64. 8 waves in 2Mx4N grid; wave-tile 32x128.
// A: fp32 staged via global_load_lds (double-buffered, source-swizzled),
//    converted to bf16 at fragment read. B: direct from L2 (pre-tiled Btt).
// ---------------------------------------------------------------------------
__device__ __forceinline__ short8 cvt8v(f32x4 x, f32x4 y) {
    union { short8 v; __hip_bfloat16 h[8]; } u;
    u.h[0] = __float2bfloat16(x[0]);
    u.h[1] = __float2bfloat16(x[1]);
    u.h[2] = __float2bfloat16(x[2]);
    u.h[3] = __float2bfloat16(x[3]);
    u.h[4] = __float2bfloat16(y[0]);
    u.h[5] = __float2bfloat16(y[1]);
    u.h[6] = __float2bfloat16(y[2]);
    u.h[7] = __float2bfloat16(y[3]);
    return u.v;
}

__global__ __launch_bounds__(512, 2) void e_kernel(const float* __restrict__ enc,
                                                   const short* __restrict__ Btt,
                                                   const float* __restrict__ att2f,
                                                   const float* __restrict__ W_att,
                                                   float* __restrict__ e_out) {
    const int tid  = threadIdx.x;
    const int lane = tid & 63;
    const int wv   = tid >> 6;   // 0..7
    const int wm   = wv >> 2;    // 0..1 : row half
    const int wn   = wv & 3;     // 0..3 : 128-col slice
    const int l15  = lane & 15;
    const int kg   = lane >> 4;  // 0..3
    const int M0   = blockIdx.x * BM;

    // A tile: fp32 [2][64 rows][64 cols], 16B-unit col swizzle u^=((row&3)<<1)
    __shared__ __attribute__((aligned(16))) float Asm[2][64 * 64];
    __shared__ float ebuf[4][64];

    // --- staging addresses (global_load_lds, 2 passes x 16B/lane) ---
    // pass p: LDS unit = p*512 + wv*64 + lane  -> row = unit>>4, c16 = lane&15
    const int r0 = wv * 4 + (lane >> 4);           // p=0 row
    const int c16s = lane & 15;
    const float* src0 = enc + (size_t)(M0 + r0) * ENC_DIM + ((c16s ^ ((r0 & 3) << 1)) << 2);
    const int r1 = r0 + 32;                        // p=1 row
    const float* src1 = enc + (size_t)(M0 + r1) * ENC_DIM + ((c16s ^ ((r1 & 3) << 1)) << 2);
    float* dst0 = &Asm[0][0] + (size_t)(wv * 64 + lane) * 4;
    float* dst1 = dst0 + 512 * 4;

    // --- B fragment base (shorts) ---
    // addr = ((step*2+kh)*512 + wn*128 + nf*16 + l15)*32 + kg*8
    const short* pb = Btt + (wn * 128 + l15) * 32 + kg * 8;

    f32x4 acc[2][8];
    #pragma unroll
    for (int i = 0; i < 2; ++i)
        #pragma unroll
        for (int j = 0; j < 8; ++j)
            acc[i][j] = (f32x4){0.f, 0.f, 0.f, 0.f};

    // prologue: stage step 0 into buf 0
    gll16(src0, dst0);
    gll16(src1, dst1);
    __syncthreads();

    int cur = 0;
    for (int step = 0; step < NSTEP; ++step) {
        if (step + 1 < NSTEP) {  // prefetch next A tile into other buffer
            const int koff = (step + 1) * BK;
            float* d0 = &Asm[cur ^ 1][0] + (size_t)(wv * 64 + lane) * 4;
            gll16(src0 + koff, d0);
            gll16(src1 + koff, d0 + 512 * 4);
        }
        const short* pbs = pb + (size_t)step * 32768;
        const float* As = &Asm[cur][0];
        #pragma unroll
        for (int kh = 0; kh < 2; ++kh) {
            // B fragments (L2): 8 x 16B/lane, contiguous per 16-lane group
            short8 bf[8];
            #pragma unroll
            for (int nf = 0; nf < 8; ++nf)
                bf[nf] = *(const short8*)(pbs + kh * 16384 + nf * 512);
            // A fragments from LDS (+ fp32->bf16)
            short8 af[2];
            #pragma unroll
            for (int mf = 0; mf < 2; ++mf) {
                const int r = wm * 32 + mf * 16 + l15;
                const int u0 = (kh * 8 + kg * 2) ^ ((r & 3) << 1);
                const float* lp = As + r * 64 + u0 * 4;
                f32x4 x = *(const f32x4*)lp;
                f32x4 y = *(const f32x4*)(lp + 4);
                af[mf] = cvt8v(x, y);
            }
            #pragma unroll
            for (int mf = 0; mf < 2; ++mf)
                #pragma unroll
                for (int nf = 0; nf < 8; ++nf)
                    acc[mf][nf] = __builtin_amdgcn_mfma_f32_16x16x32_bf16(af[mf], bf[nf], acc[mf][nf], 0, 0, 0);
        }
        __syncthreads();
        cur ^= 1;
    }

    // epilogue: + att2, relu, * W_att, reduce over n
    float wat[8];
    #pragma unroll
    for (int nf = 0; nf < 8; ++nf) wat[nf] = W_att[wn * 128 + nf * 16 + l15];

    #pragma unroll
    for (int mf = 0; mf < 2; ++mf) {
        #pragma unroll
        for (int rr = 0; rr < 4; ++rr) {
            const int ml = wm * 32 + mf * 16 + kg * 4 + rr;  // local row 0..63
            const int bb = (M0 + ml) / NP;
            const float* arow = att2f + (size_t)bb * ATT_DIM + wn * 128 + l15;
            float s = 0.f;
            #pragma unroll
            for (int nf = 0; nf < 8; ++nf) {
                float v = acc[mf][nf][rr] + arow[nf * 16];
                s += fmaxf(v, 0.f) * wat[nf];
            }
            s += __shfl_xor(s, 1);
            s += __shfl_xor(s, 2);
            s += __shfl_xor(s, 4);
            s += __shfl_xor(s, 8);
            if (l15 == 0) ebuf[wn][ml] = s;
        }
    }
    __syncthreads();
    if (tid < 64)
        e_out[M0 + tid] = ebuf[0][tid] + ebuf[1][tid] + ebuf[2][tid] + ebuf[3][tid];
}

// ---------------------------------------------------------------------------
// Kernel 3: per-batch softmax over 196 pixels + z[b,:] = sum_p alpha[b,p]*enc[b,p,:]
// grid (256, 2): 1024-col chunks, float4/thread, dual accumulators.
// ---------------------------------------------------------------------------
__global__ __launch_bounds__(256) void z_kernel(const float* __restrict__ enc,
                                                const float* __restrict__ e,
                                                float* __restrict__ z,
                                                float* __restrict__ alpha) {
    const int b  = blockIdx.x;
    const int cb = blockIdx.y;
    const int t  = threadIdx.x;
    __shared__ float al[NP];
    __shared__ float red[4];

    float ev = (t < NP) ? e[(size_t)b * NP + t] : -1e30f;
    float m = ev;
    #pragma unroll
    for (int o = 32; o > 0; o >>= 1) m = fmaxf(m, __shfl_xor(m, o));
    if ((t & 63) == 0) red[t >> 6] = m;
    __syncthreads();
    m = fmaxf(fmaxf(red[0], red[1]), fmaxf(red[2], red[3]));
    __syncthreads();
    float ex = (t < NP) ? __expf(ev - m) : 0.f;
    float s = ex;
    #pragma unroll
    for (int o = 32; o > 0; o >>= 1) s += __shfl_xor(s, o);
    if ((t & 63) == 0) red[t >> 6] = s;
    __syncthreads();
    s = red[0] + red[1] + red[2] + red[3];
    const float a = ex * (1.0f / s);
    if (t < NP) {
        al[t] = a;
        if (cb == 0) alpha[(size_t)b * NP + t] = a;
    }
    __syncthreads();

    const int c0 = cb * 1024 + t * 4;
    const float4* ep = (const float4*)(enc + (size_t)b * NP * ENC_DIM + c0);
    float4 z0 = make_float4(0.f, 0.f, 0.f, 0.f);
    float4 z1 = make_float4(0.f, 0.f, 0.f, 0.f);
    #pragma unroll 4
    for (int p = 0; p < NP; p += 2) {
        const float a0 = al[p];
        const float a1 = al[p + 1];
        const float4 v0 = ep[(size_t)p * (ENC_DIM / 4)];
        const float4 v1 = ep[(size_t)(p + 1) * (ENC_DIM / 4)];
        z0.x += a0 * v0.x; z0.y += a0 * v0.y; z0.z += a0 * v0.z; z0.w += a0 * v0.w;
        z1.x += a1 * v1.x; z1.y += a1 * v1.y; z1.z += a1 * v1.z; z1.w += a1 * v1.w;
    }
    z0.x += z1.x; z0.y += z1.y; z0.z += z1.z; z0.w += z1.w;
    *(float4*)(z + (size_t)b * ENC_DIM + c0) = z0;
}

// ---------------------------------------------------------------------------
extern "C" void kernel_launch(void* const* d_in, const int* in_sizes, int n_in,
                              void* d_out, int out_size, void* d_ws, size_t ws_size,
                              hipStream_t stream) {
    const float* enc   = (const float*)d_in[0];  // (256,196,2048)
    const float* dec   = (const float*)d_in[1];  // (256,512)
    const float* W_enc = (const float*)d_in[2];  // (2048,512)
    const float* b_enc = (const float*)d_in[3];  // (512)
    const float* W_dec = (const float*)d_in[4];  // (512,512)
    const float* b_dec = (const float*)d_in[5];  // (512)
    const float* W_att = (const float*)d_in[6];  // (512,1)
    // d_in[7] = b_att: softmax-invariant, unused.

    float* z     = (float*)d_out;                 // 256*2048
    float* alpha = z + (size_t)NB * ENC_DIM;      // 256*196

    char* ws = (char*)d_ws;
    __hip_bfloat16* Btt = (__hip_bfloat16*)ws;                        // 2 MB
    float* att2f        = (float*)(ws + 2 * 1024 * 1024);             // 512 KB
    float* e            = (float*)(ws + 2 * 1024 * 1024 + 512 * 1024);// 200 KB

    prep_kernel<<<768, 256, 0, stream>>>(W_enc, Btt, dec, W_dec, b_dec, b_enc, att2f);
    e_kernel<<<M_TOT / BM, 512, 0, stream>>>(enc, (const short*)Btt, att2f, W_att, e);
    z_kernel<<<dim3(NB, 2), 256, 0, stream>>>(enc, e, z, alpha);
}

// Round 5
// 387.854 us; speedup vs baseline: 1.1751x; 1.1751x over previous
//
#include <hip/hip_runtime.h>
#include <hip/hip_bf16.h>

#define ENC_DIM 2048
#define DEC_DIM 512
#define ATT_DIM 512
#define NB 256
#define NP 196
#define M_TOT (NB * NP)   // 50176 = 784 * 64
#define BM 64
#define BK 32
#define NSTEP (ENC_DIM / BK)  // 64

typedef __attribute__((ext_vector_type(8))) short short8;
typedef __attribute__((ext_vector_type(4))) short short4s;
typedef __attribute__((ext_vector_type(4))) float f32x4;

// async global->LDS, 16 B/lane; dst = wave-uniform base, HW adds lane*16
__device__ __forceinline__ void gll16(const short* g, short* l) {
    __builtin_amdgcn_global_load_lds((const __attribute__((address_space(1))) void*)g,
                                     (__attribute__((address_space(3))) void*)l,
                                     16, 0, 0);
}

__device__ __forceinline__ short4s cvt4(f32x4 v) {
    union { short4s s; __hip_bfloat16 h[4]; } u;
    u.h[0] = __float2bfloat16(v[0]);
    u.h[1] = __float2bfloat16(v[1]);
    u.h[2] = __float2bfloat16(v[2]);
    u.h[3] = __float2bfloat16(v[3]);
    return u.s;
}

// ---------------------------------------------------------------------------
// Kernel 1 (fused): blocks [0,512): pack W_enc into Btt, ordered EXACTLY as the
// e_kernel's linear gll staging order per K-step:
//   step s (BK=32), unit U (16B) = cb*64 + kg*16 + l15 :
//     holds bf16 W[k = s*32+kg*8 .. +8][col = cb*16+l15]
// so LDS ends up as [cb][kg][l15][8] and every B fragment is a contiguous 1KB.
// blocks [512,768): att2f[b][n] = dec[b]@W_dec[:,n] + b_dec[n] + b_enc[n]
// ---------------------------------------------------------------------------
__global__ __launch_bounds__(256) void prep_kernel(const float* __restrict__ W,
                                                   __hip_bfloat16* __restrict__ Btt,
                                                   const float* __restrict__ dec,
                                                   const float* __restrict__ W_dec,
                                                   const float* __restrict__ b_dec,
                                                   const float* __restrict__ b_enc,
                                                   float* __restrict__ att2f) {
    __shared__ float ds[DEC_DIM];
    if (blockIdx.x < 512) {
        const int gid = blockIdx.x * 256 + threadIdx.x;  // 0..131071
        const int s   = gid >> 11;        // K-step 0..63
        const int u   = gid & 2047;       // unit within step
        const int cb  = u >> 6;           // col block 0..31
        const int kg  = (u >> 4) & 3;
        const int l15 = u & 15;
        const int col = cb * 16 + l15;
        const int k0  = s * 32 + kg * 8;
        union { short8 v; __hip_bfloat16 h[8]; } x;
        #pragma unroll
        for (int i = 0; i < 8; ++i)
            x.h[i] = __float2bfloat16(W[(size_t)(k0 + i) * ATT_DIM + col]);
        *(short8*)((short*)Btt + (size_t)gid * 8) = x.v;
    } else {
        const int b = blockIdx.x - 512;
        const int t = threadIdx.x;
        ds[t]       = dec[(size_t)b * DEC_DIM + t];
        ds[t + 256] = dec[(size_t)b * DEC_DIM + t + 256];
        __syncthreads();
        #pragma unroll
        for (int j = 0; j < 2; ++j) {
            const int n = t + j * 256;
            float s = 0.f;
            #pragma unroll 8
            for (int k = 0; k < DEC_DIM; ++k)
                s += ds[k] * W_dec[(size_t)k * ATT_DIM + n];
            att2f[(size_t)b * ATT_DIM + n] = s + b_dec[n] + b_enc[n];
        }
    }
}

// ---------------------------------------------------------------------------
// Kernel 2: e[m] = sum_n relu(enc[m,:]@W_enc[:,n] + att2f[b,n]) * W_att[n]
// BM=64 x BN=512 x BK=32; 8 waves (2M x 4N), wave tile 32x128.
// B: global_load_lds from pre-permuted Btt (fragment-contiguous LDS, 0-conflict).
// A: reg-staged fp32 -> cvt bf16 -> LDS, 2-step-deep prefetch (T14).
// All fragment reads are contiguous 1KB wave reads.
// ---------------------------------------------------------------------------
__global__ __launch_bounds__(512, 2) void e_kernel(const float* __restrict__ enc,
                                                   const short* __restrict__ Btt,
                                                   const float* __restrict__ att2f,
                                                   const float* __restrict__ W_att,
                                                   float* __restrict__ e_out) {
    __shared__ __attribute__((aligned(16))) short Bs[2][16384];  // 2 x 32 KB
    __shared__ __attribute__((aligned(16))) short As[2][2048];   // 2 x 4 KB
    __shared__ float ebuf[4][64];

    const int tid  = threadIdx.x;
    const int lane = tid & 63;
    const int wv   = tid >> 6;   // 0..7
    const int wm   = wv >> 2;    // 0..1
    const int wn   = wv & 3;     // 0..3
    const int l15  = lane & 15;
    const int kg   = lane >> 4;  // 0..3
    const int M0   = blockIdx.x * BM;

    // A staging: thread -> (row = tid>>3, k-quad q = tid&7)
    const int arow = tid >> 3;
    const int aq   = tid & 7;
    const float* asrc = enc + (size_t)(M0 + arow) * ENC_DIM + aq * 4;
    // LDS short index: [mf=row>>4][kg=q>>1][l15=row&15][h=q&1]
    const int awr = (arow >> 4) * 512 + (aq >> 1) * 128 + (arow & 15) * 8 + (aq & 1) * 4;

    // B staging: per wave, 4 gll calls; call g covers LDS units (g*8+wv)*64 + lane
    const short* bsrc = Btt + (size_t)wv * 512 + lane * 8;

    f32x4 acc[2][8];
    #pragma unroll
    for (int i = 0; i < 2; ++i)
        #pragma unroll
        for (int j = 0; j < 8; ++j)
            acc[i][j] = (f32x4){0.f, 0.f, 0.f, 0.f};

    // prologue: stage step 0, preload A(1)
    #pragma unroll
    for (int g = 0; g < 4; ++g)
        gll16(bsrc + g * 4096, &Bs[0][(g * 8 + wv) * 512]);
    {
        f32x4 a0 = *(const f32x4*)asrc;
        *(short4s*)&As[0][awr] = cvt4(a0);
    }
    f32x4 avP = *(const f32x4*)(asrc + BK);
    __syncthreads();

    for (int s = 0; s < NSTEP; ++s) {
        const int cur = s & 1;
        const int nxt = cur ^ 1;
        // prefetch: B(s+1) via gll, A(s+2) to reg
        if (s + 1 < NSTEP) {
            const short* bs = bsrc + (size_t)(s + 1) * 16384;
            #pragma unroll
            for (int g = 0; g < 4; ++g)
                gll16(bs + g * 4096, &Bs[nxt][(g * 8 + wv) * 512]);
        }
        f32x4 avN;
        if (s + 2 < NSTEP)
            avN = *(const f32x4*)(asrc + (size_t)(s + 2) * BK);

        // fragments (all contiguous 1KB wave reads)
        short8 af[2];
        #pragma unroll
        for (int mf = 0; mf < 2; ++mf)
            af[mf] = *(const short8*)&As[cur][(wm * 2 + mf) * 512 + lane * 8];
        short8 bf8[8];
        #pragma unroll
        for (int nf = 0; nf < 8; ++nf)
            bf8[nf] = *(const short8*)&Bs[cur][(wn * 8 + nf) * 512 + lane * 8];

        #pragma unroll
        for (int mf = 0; mf < 2; ++mf)
            #pragma unroll
            for (int nf = 0; nf < 8; ++nf)
                acc[mf][nf] = __builtin_amdgcn_mfma_f32_16x16x32_bf16(af[mf], bf8[nf], acc[mf][nf], 0, 0, 0);

        // write-late: A(s+1) (loaded 2 steps ago, long arrived)
        if (s + 1 < NSTEP) {
            *(short4s*)&As[nxt][awr] = cvt4(avP);
            avP = avN;
        }
        __syncthreads();
    }

    // epilogue: + att2, relu, * W_att, reduce over n
    float wat[8];
    #pragma unroll
    for (int nf = 0; nf < 8; ++nf) wat[nf] = W_att[wn * 128 + nf * 16 + l15];

    #pragma unroll
    for (int mf = 0; mf < 2; ++mf) {
        #pragma unroll
        for (int rr = 0; rr < 4; ++rr) {
            const int ml = wm * 32 + mf * 16 + kg * 4 + rr;   // local row
            const int bb = (M0 + ml) / NP;
            const float* arow2 = att2f + (size_t)bb * ATT_DIM + wn * 128 + l15;
            float sv = 0.f;
            #pragma unroll
            for (int nf = 0; nf < 8; ++nf) {
                float v = acc[mf][nf][rr] + arow2[nf * 16];
                sv += fmaxf(v, 0.f) * wat[nf];
            }
            sv += __shfl_xor(sv, 1);
            sv += __shfl_xor(sv, 2);
            sv += __shfl_xor(sv, 4);
            sv += __shfl_xor(sv, 8);
            if (l15 == 0) ebuf[wn][ml] = sv;
        }
    }
    __syncthreads();
    if (tid < 64)
        e_out[M0 + tid] = ebuf[0][tid] + ebuf[1][tid] + ebuf[2][tid] + ebuf[3][tid];
}

// ---------------------------------------------------------------------------
// Kernel 3: per-batch softmax over 196 pixels + z[b,:] = sum_p alpha[b,p]*enc[b,p,:]
// grid (256, 2): 1024-col chunks, float4/thread, dual accumulators.
// ---------------------------------------------------------------------------
__global__ __launch_bounds__(256) void z_kernel(const float* __restrict__ enc,
                                                const float* __restrict__ e,
                                                float* __restrict__ z,
                                                float* __restrict__ alpha) {
    const int b  = blockIdx.x;
    const int cb = blockIdx.y;
    const int t  = threadIdx.x;
    __shared__ float al[NP];
    __shared__ float red[4];

    float ev = (t < NP) ? e[(size_t)b * NP + t] : -1e30f;
    float m = ev;
    #pragma unroll
    for (int o = 32; o > 0; o >>= 1) m = fmaxf(m, __shfl_xor(m, o));
    if ((t & 63) == 0) red[t >> 6] = m;
    __syncthreads();
    m = fmaxf(fmaxf(red[0], red[1]), fmaxf(red[2], red[3]));
    __syncthreads();
    float ex = (t < NP) ? __expf(ev - m) : 0.f;
    float s = ex;
    #pragma unroll
    for (int o = 32; o > 0; o >>= 1) s += __shfl_xor(s, o);
    if ((t & 63) == 0) red[t >> 6] = s;
    __syncthreads();
    s = red[0] + red[1] + red[2] + red[3];
    const float a = ex * (1.0f / s);
    if (t < NP) {
        al[t] = a;
        if (cb == 0) alpha[(size_t)b * NP + t] = a;
    }
    __syncthreads();

    const int c0 = cb * 1024 + t * 4;
    const float4* ep = (const float4*)(enc + (size_t)b * NP * ENC_DIM + c0);
    float4 z0 = make_float4(0.f, 0.f, 0.f, 0.f);
    float4 z1 = make_float4(0.f, 0.f, 0.f, 0.f);
    #pragma unroll 4
    for (int p = 0; p < NP; p += 2) {
        const float a0 = al[p];
        const float a1 = al[p + 1];
        const float4 v0 = ep[(size_t)p * (ENC_DIM / 4)];
        const float4 v1 = ep[(size_t)(p + 1) * (ENC_DIM / 4)];
        z0.x += a0 * v0.x; z0.y += a0 * v0.y; z0.z += a0 * v0.z; z0.w += a0 * v0.w;
        z1.x += a1 * v1.x; z1.y += a1 * v1.y; z1.z += a1 * v1.z; z1.w += a1 * v1.w;
    }
    z0.x += z1.x; z0.y += z1.y; z0.z += z1.z; z0.w += z1.w;
    *(float4*)(z + (size_t)b * ENC_DIM + c0) = z0;
}

// ---------------------------------------------------------------------------
extern "C" void kernel_launch(void* const* d_in, const int* in_sizes, int n_in,
                              void* d_out, int out_size, void* d_ws, size_t ws_size,
                              hipStream_t stream) {
    const float* enc   = (const float*)d_in[0];  // (256,196,2048)
    const float* dec   = (const float*)d_in[1];  // (256,512)
    const float* W_enc = (const float*)d_in[2];  // (2048,512)
    const float* b_enc = (const float*)d_in[3];  // (512)
    const float* W_dec = (const float*)d_in[4];  // (512,512)
    const float* b_dec = (const float*)d_in[5];  // (512)
    const float* W_att = (const float*)d_in[6];  // (512,1)
    // d_in[7] = b_att: softmax-invariant, unused.

    float* z     = (float*)d_out;                 // 256*2048
    float* alpha = z + (size_t)NB * ENC_DIM;      // 256*196

    char* ws = (char*)d_ws;
    __hip_bfloat16* Btt = (__hip_bfloat16*)ws;                        // 2 MB
    float* att2f        = (float*)(ws + 2 * 1024 * 1024);             // 512 KB
    float* e            = (float*)(ws + 2 * 1024 * 1024 + 512 * 1024);// 200 KB

    prep_kernel<<<768, 256, 0, stream>>>(W_enc, Btt, dec, W_dec, b_dec, b_enc, att2f);
    e_kernel<<<M_TOT / BM, 512, 0, stream>>>(enc, (const short*)Btt, att2f, W_att, e);
    z_kernel<<<dim3(NB, 2), 256, 0, stream>>>(enc, e, z, alpha);
}

// Round 6
// 312.960 us; speedup vs baseline: 1.4563x; 1.2393x over previous
//
#include <hip/hip_runtime.h>
#include <hip/hip_bf16.h>

#define ENC_DIM 2048
#define DEC_DIM 512
#define ATT_DIM 512
#define NB 256
#define NP 196
#define M_TOT (NB * NP)   // 50176 = 784 * 64
#define BM 64
#define BK 32
#define NSTEP (ENC_DIM / BK)  // 64

typedef __attribute__((ext_vector_type(8))) short short8;
typedef __attribute__((ext_vector_type(4))) short short4s;
typedef __attribute__((ext_vector_type(4))) float f32x4;

// async global->LDS, 16 B/lane; dst = wave-uniform base, HW adds lane*16
__device__ __forceinline__ void gll16(const short* g, short* l) {
    __builtin_amdgcn_global_load_lds((const __attribute__((address_space(1))) void*)g,
                                     (__attribute__((address_space(3))) void*)l,
                                     16, 0, 0);
}

__device__ __forceinline__ short4s cvt4(f32x4 v) {
    union { short4s s; __hip_bfloat16 h[4]; } u;
    u.h[0] = __float2bfloat16(v[0]);
    u.h[1] = __float2bfloat16(v[1]);
    u.h[2] = __float2bfloat16(v[2]);
    u.h[3] = __float2bfloat16(v[3]);
    return u.s;
}

// ---------------------------------------------------------------------------
// Kernel 1 (fused): blocks [0,512): pack W_enc into Btt in the e_kernel's
// linear gll staging order (LDS ends up [cb][kg][l15][8]; every B fragment a
// contiguous 1KB). blocks [512,768): att2f = dec@W_dec + b_dec + b_enc.
// ---------------------------------------------------------------------------
__global__ __launch_bounds__(256) void prep_kernel(const float* __restrict__ W,
                                                   __hip_bfloat16* __restrict__ Btt,
                                                   const float* __restrict__ dec,
                                                   const float* __restrict__ W_dec,
                                                   const float* __restrict__ b_dec,
                                                   const float* __restrict__ b_enc,
                                                   float* __restrict__ att2f) {
    __shared__ float ds[DEC_DIM];
    if (blockIdx.x < 512) {
        const int gid = blockIdx.x * 256 + threadIdx.x;  // 0..131071
        const int s   = gid >> 11;        // K-step 0..63
        const int u   = gid & 2047;       // unit within step
        const int cb  = u >> 6;           // col block 0..31
        const int kg  = (u >> 4) & 3;
        const int l15 = u & 15;
        const int col = cb * 16 + l15;
        const int k0  = s * 32 + kg * 8;
        union { short8 v; __hip_bfloat16 h[8]; } x;
        #pragma unroll
        for (int i = 0; i < 8; ++i)
            x.h[i] = __float2bfloat16(W[(size_t)(k0 + i) * ATT_DIM + col]);
        *(short8*)((short*)Btt + (size_t)gid * 8) = x.v;
    } else {
        const int b = blockIdx.x - 512;
        const int t = threadIdx.x;
        ds[t]       = dec[(size_t)b * DEC_DIM + t];
        ds[t + 256] = dec[(size_t)b * DEC_DIM + t + 256];
        __syncthreads();
        #pragma unroll
        for (int j = 0; j < 2; ++j) {
            const int n = t + j * 256;
            float s = 0.f;
            #pragma unroll 8
            for (int k = 0; k < DEC_DIM; ++k)
                s += ds[k] * W_dec[(size_t)k * ATT_DIM + n];
            att2f[(size_t)b * ATT_DIM + n] = s + b_dec[n] + b_enc[n];
        }
    }
}

// ---------------------------------------------------------------------------
// Kernel 2: e[m] = sum_n relu(enc[m,:]@W_enc[:,n] + att2f[b,n]) * W_att[n]
// BM=64 x BN=512 x BK=32; 8 waves 1Mx8N, wave tile 64x64 (min LDS re-reads).
// Counted-vmcnt schedule: raw s_barrier, entry s_waitcnt vmcnt(1) (never 0),
// B(s+1) glls + asm A(s+3) load stay in flight across barriers (T3/T4).
// ---------------------------------------------------------------------------
__global__ __launch_bounds__(512, 4) void e_kernel(const float* __restrict__ enc,
                                                   const short* __restrict__ Btt,
                                                   const float* __restrict__ att2f,
                                                   const float* __restrict__ W_att,
                                                   float* __restrict__ e_out) {
    __shared__ __attribute__((aligned(16))) short Bs[2][16384];  // 2 x 32 KB
    __shared__ __attribute__((aligned(16))) short As[2][2048];   // 2 x 4 KB
    __shared__ float ebuf[8][64];

    const int tid  = threadIdx.x;
    const int lane = tid & 63;
    const int wv   = tid >> 6;   // 0..7 : 64-col slice
    const int l15  = lane & 15;
    const int kg   = lane >> 4;  // 0..3
    const int M0   = blockIdx.x * BM;

    // A staging: thread -> (row = tid>>3, k-quad q = tid&7)
    const int arow = tid >> 3;
    const int aq   = tid & 7;
    const float* asrc = enc + (size_t)(M0 + arow) * ENC_DIM + aq * 4;
    // LDS short index: [mf=row>>4][kg=q>>1][l15=row&15][h=q&1]
    const int awr = (arow >> 4) * 512 + (aq >> 1) * 128 + (arow & 15) * 8 + (aq & 1) * 4;

    // B staging: per wave, 4 gll calls; call g covers LDS units (g*8+wv)*64+lane
    const short* bsrc = Btt + (size_t)wv * 512 + lane * 8;

    f32x4 acc[4][4];
    #pragma unroll
    for (int i = 0; i < 4; ++i)
        #pragma unroll
        for (int j = 0; j < 4; ++j)
            acc[i][j] = (f32x4){0.f, 0.f, 0.f, 0.f};

    // ---- prologue: stage step 0; A-pipeline depth 3 ----
    #pragma unroll
    for (int g = 0; g < 4; ++g)
        gll16(bsrc + g * 4096, &Bs[0][(g * 8 + wv) * 512]);
    {
        f32x4 a0 = *(const f32x4*)asrc;
        *(short4s*)&As[0][awr] = cvt4(a0);
    }
    f32x4 avP, avQ;  // A(1), A(2)
    asm volatile("global_load_dwordx4 %0, %1, off" : "=v"(avP)
                 : "v"((unsigned long long)(asrc + 1 * BK)));
    asm volatile("global_load_dwordx4 %0, %1, off" : "=v"(avQ)
                 : "v"((unsigned long long)(asrc + 2 * BK)));
    asm volatile("s_waitcnt lgkmcnt(0)" ::: "memory");

    for (int s = 0; s < NSTEP; ++s) {
        const int cur = s & 1;
        const int nxt = cur ^ 1;
        __builtin_amdgcn_s_barrier();
        // entry wait: drains B(s) + A(s+1); leaves newest (A(s+2)) in flight
        asm volatile("s_waitcnt vmcnt(1)" ::: "memory");
        __builtin_amdgcn_sched_barrier(0);

        // stage(s+1): B glls into Bs[nxt]  (wrap at tail; harmless re-stage)
        const int sb = (s + 1) & (NSTEP - 1);
        const short* bs = bsrc + (size_t)sb * 16384;
        #pragma unroll
        for (int g = 0; g < 4; ++g)
            gll16(bs + g * 4096, &Bs[nxt][(g * 8 + wv) * 512]);
        // A(s+3) load, issued AFTER the glls (asm pins order)
        const int sa = (s + 3) & (NSTEP - 1);
        f32x4 avN;
        asm volatile("global_load_dwordx4 %0, %1, off" : "=v"(avN)
                     : "v"((unsigned long long)(asrc + sa * BK)));

        // ds_write A(s+1) into As[nxt] (readers of As[nxt] done: entry barrier)
        *(short4s*)&As[nxt][awr] = cvt4(avP);
        avP = avQ; avQ = avN;

        // fragments (contiguous 1KB wave reads, conflict-free)
        short8 af[4];
        #pragma unroll
        for (int mf = 0; mf < 4; ++mf)
            af[mf] = *(const short8*)&As[cur][mf * 512 + lane * 8];
        short8 bf[4];
        #pragma unroll
        for (int nf = 0; nf < 4; ++nf)
            bf[nf] = *(const short8*)&Bs[cur][(wv * 4 + nf) * 512 + lane * 8];

        __builtin_amdgcn_s_setprio(1);
        #pragma unroll
        for (int mf = 0; mf < 4; ++mf)
            #pragma unroll
            for (int nf = 0; nf < 4; ++nf)
                acc[mf][nf] = __builtin_amdgcn_mfma_f32_16x16x32_bf16(af[mf], bf[nf], acc[mf][nf], 0, 0, 0);
        __builtin_amdgcn_s_setprio(0);

        // ds_write visible to other waves before next barrier; NO vmem drain
        asm volatile("s_waitcnt lgkmcnt(0)" ::: "memory");
        __builtin_amdgcn_sched_barrier(0);
    }

    // epilogue: + att2, relu, * W_att, reduce over n
    float wat[4];
    #pragma unroll
    for (int nf = 0; nf < 4; ++nf) wat[nf] = W_att[wv * 64 + nf * 16 + l15];

    #pragma unroll
    for (int mf = 0; mf < 4; ++mf) {
        #pragma unroll
        for (int rr = 0; rr < 4; ++rr) {
            const int ml = mf * 16 + kg * 4 + rr;   // local row 0..63
            const int bb = (M0 + ml) / NP;
            const float* arow2 = att2f + (size_t)bb * ATT_DIM + wv * 64 + l15;
            float sv = 0.f;
            #pragma unroll
            for (int nf = 0; nf < 4; ++nf) {
                float v = acc[mf][nf][rr] + arow2[nf * 16];
                sv += fmaxf(v, 0.f) * wat[nf];
            }
            sv += __shfl_xor(sv, 1);
            sv += __shfl_xor(sv, 2);
            sv += __shfl_xor(sv, 4);
            sv += __shfl_xor(sv, 8);
            if (l15 == 0) ebuf[wv][ml] = sv;
        }
    }
    __syncthreads();
    if (tid < 64) {
        float sv = 0.f;
        #pragma unroll
        for (int w = 0; w < 8; ++w) sv += ebuf[w][tid];
        e_out[M0 + tid] = sv;
    }
}

// ---------------------------------------------------------------------------
// Kernel 3: per-batch softmax over 196 pixels + z[b,:] = sum_p alpha[b,p]*enc[b,p,:]
// grid (256, 2): 1024-col chunks, float4/thread, dual accumulators.
// ---------------------------------------------------------------------------
__global__ __launch_bounds__(256) void z_kernel(const float* __restrict__ enc,
                                                const float* __restrict__ e,
                                                float* __restrict__ z,
                                                float* __restrict__ alpha) {
    const int b  = blockIdx.x;
    const int cb = blockIdx.y;
    const int t  = threadIdx.x;
    __shared__ float al[NP];
    __shared__ float red[4];

    float ev = (t < NP) ? e[(size_t)b * NP + t] : -1e30f;
    float m = ev;
    #pragma unroll
    for (int o = 32; o > 0; o >>= 1) m = fmaxf(m, __shfl_xor(m, o));
    if ((t & 63) == 0) red[t >> 6] = m;
    __syncthreads();
    m = fmaxf(fmaxf(red[0], red[1]), fmaxf(red[2], red[3]));
    __syncthreads();
    float ex = (t < NP) ? __expf(ev - m) : 0.f;
    float s = ex;
    #pragma unroll
    for (int o = 32; o > 0; o >>= 1) s += __shfl_xor(s, o);
    if ((t & 63) == 0) red[t >> 6] = s;
    __syncthreads();
    s = red[0] + red[1] + red[2] + red[3];
    const float a = ex * (1.0f / s);
    if (t < NP) {
        al[t] = a;
        if (cb == 0) alpha[(size_t)b * NP + t] = a;
    }
    __syncthreads();

    const int c0 = cb * 1024 + t * 4;
    const float4* ep = (const float4*)(enc + (size_t)b * NP * ENC_DIM + c0);
    float4 z0 = make_float4(0.f, 0.f, 0.f, 0.f);
    float4 z1 = make_float4(0.f, 0.f, 0.f, 0.f);
    #pragma unroll 4
    for (int p = 0; p < NP; p += 2) {
        const float a0 = al[p];
        const float a1 = al[p + 1];
        const float4 v0 = ep[(size_t)p * (ENC_DIM / 4)];
        const float4 v1 = ep[(size_t)(p + 1) * (ENC_DIM / 4)];
        z0.x += a0 * v0.x; z0.y += a0 * v0.y; z0.z += a0 * v0.z; z0.w += a0 * v0.w;
        z1.x += a1 * v1.x; z1.y += a1 * v1.y; z1.z += a1 * v1.z; z1.w += a1 * v1.w;
    }
    z0.x += z1.x; z0.y += z1.y; z0.z += z1.z; z0.w += z1.w;
    *(float4*)(z + (size_t)b * ENC_DIM + c0) = z0;
}

// ---------------------------------------------------------------------------
extern "C" void kernel_launch(void* const* d_in, const int* in_sizes, int n_in,
                              void* d_out, int out_size, void* d_ws, size_t ws_size,
                              hipStream_t stream) {
    const float* enc   = (const float*)d_in[0];  // (256,196,2048)
    const float* dec   = (const float*)d_in[1];  // (256,512)
    const float* W_enc = (const float*)d_in[2];  // (2048,512)
    const float* b_enc = (const float*)d_in[3];  // (512)
    const float* W_dec = (const float*)d_in[4];  // (512,512)
    const float* b_dec = (const float*)d_in[5];  // (512)
    const float* W_att = (const float*)d_in[6];  // (512,1)
    // d_in[7] = b_att: softmax-invariant, unused.

    float* z     = (float*)d_out;                 // 256*2048
    float* alpha = z + (size_t)NB * ENC_DIM;      // 256*196

    char* ws = (char*)d_ws;
    __hip_bfloat16* Btt = (__hip_bfloat16*)ws;                        // 2 MB
    float* att2f        = (float*)(ws + 2 * 1024 * 1024);             // 512 KB
    float* e            = (float*)(ws + 2 * 1024 * 1024 + 512 * 1024);// 200 KB

    prep_kernel<<<768, 256, 0, stream>>>(W_enc, Btt, dec, W_dec, b_dec, b_enc, att2f);
    e_kernel<<<M_TOT / BM, 512, 0, stream>>>(enc, (const short*)Btt, att2f, W_att, e);
    z_kernel<<<dim3(NB, 2), 256, 0, stream>>>(enc, e, z, alpha);
}